// Round 1
// baseline (906.419 us; speedup 1.0000x reference)
//
#include <hip/hip_runtime.h>

typedef __attribute__((ext_vector_type(8))) short short8;
typedef __attribute__((ext_vector_type(4))) float f32x4;
typedef __attribute__((ext_vector_type(4))) unsigned short us4;

#define LEAK 0.2f

__device__ __forceinline__ float b2f(unsigned short s) {
    unsigned u = ((unsigned)s) << 16;
    return __builtin_bit_cast(float, u);
}
__device__ __forceinline__ unsigned short f2b(float f) {
    unsigned u = __builtin_bit_cast(unsigned, f);
    u += 0x7fffu + ((u >> 16) & 1u);
    return (unsigned short)(u >> 16);
}

// bilinear resize (64,128) -> (128,256), half-pixel centers, edge-clamp
// (equivalent to jax.image.resize triangle-kernel with boundary renormalization)
__device__ __forceinline__ float up_at(const float* __restrict__ pd, int b, int i, int j) {
    float sy = i * 0.5f - 0.25f;
    float sx = j * 0.5f - 0.25f;
    float fy0 = floorf(sy), fx0 = floorf(sx);
    float fy = sy - fy0, fx = sx - fx0;
    int y0 = (int)fy0, x0 = (int)fx0;
    int y0c = min(max(y0, 0), 63), y1c = min(max(y0 + 1, 0), 63);
    int x0c = min(max(x0, 0), 127), x1c = min(max(x0 + 1, 0), 127);
    const float* p = pd + b * 64 * 128;
    float v00 = p[y0c * 128 + x0c], v01 = p[y0c * 128 + x1c];
    float v10 = p[y1c * 128 + x0c], v11 = p[y1c * 128 + x1c];
    return (1.f - fy) * ((1.f - fx) * v00 + fx * v01) + fy * ((1.f - fx) * v10 + fx * v11);
}

// faithful keras-bug warp: pixel-flat index into right.reshape(-1); cy integer => y-weights (1,0)
__device__ __forceinline__ float warp_at(const float* __restrict__ right,
                                         const float* __restrict__ pd, int b, int i, int j) {
    float up = up_at(pd, b, i, j);
    float cx = (float)j - up;
    float x0 = floorf(cx), x1 = x0 + 1.f;
    float w0 = x1 - cx, w1 = cx - x0;
    float x0s = fminf(fmaxf(x0, 0.f), 255.f);
    float x1s = fminf(fmaxf(x1, 0.f), 255.f);
    float base = (float)(b * 32768 + i * 256);
    int i0 = (int)(x0s + base);
    int i1 = (int)(x1s + base);
    return w0 * right[i0] + w1 * right[i1];
}

// Build vol [B,H,W,160] bf16: ch 0..127 = left, 128..132 = costs, 133 = up, 134..159 = 0
__global__ void prep_kernel(const float* __restrict__ left, const float* __restrict__ right,
                            const float* __restrict__ pd, short* __restrict__ vol) {
    int idx = blockIdx.x * 256 + threadIdx.x;            // pixel index
    int w = idx & 255, h = (idx >> 8) & 127, b = idx >> 15;
    const float* lp = left + (size_t)idx * 128;
    short* vp = vol + (size_t)idx * 160;
    float sum = 0.f;
#pragma unroll 8
    for (int c = 0; c < 128; c += 4) {
        float4 v = *(const float4*)(lp + c);
        sum += (v.x + v.y) + (v.z + v.w);
        us4 o;
        o.x = f2b(v.x); o.y = f2b(v.y); o.z = f2b(v.z); o.w = f2b(v.w);
        *(us4*)(vp + c) = o;
    }
    float meanleft = sum * (1.f / 128.f);
    float up = up_at(pd, b, h, w);
#pragma unroll
    for (int t = 0; t < 5; ++t) {
        int jj = w + t - 2;
        float cost = 0.f;
        if (jj >= 0 && jj < 256) cost = warp_at(right, pd, b, h, jj) * meanleft;
        vp[128 + t] = (short)f2b(cost);
    }
    vp[133] = (short)f2b(up);
#pragma unroll
    for (int c = 134; c < 160; c += 2) { vp[c] = 0; vp[c + 1] = 0; }
}

// fp32 HWIO weights -> bf16 [tap][kc][n(128)][k(32)], zero-padded in both k and n
__global__ void wconv_kernel(const float* __restrict__ k, short* __restrict__ wt,
                             int CIN, int COUT, int KC) {
    int idx = blockIdx.x * 256 + threadIdx.x;
    int total = 9 * KC * 4096;
    if (idx >= total) return;
    int kk = idx & 31;
    int n = (idx >> 5) & 127;
    int rest = idx >> 12;             // tap*KC + kc
    int kc = rest % KC, tap = rest / KC;
    int ci = kc * 32 + kk;
    float v = 0.f;
    if (ci < CIN && n < COUT) v = k[(size_t)(tap * CIN + ci) * COUT + n];
    wt[idx] = (short)f2b(v);
}

// 3x3 SAME conv, NHWC bf16, Cin = KC*32 (stored stride), Cout <= 128 (weights n-padded to 128).
// Block: 256 thr = 4 waves; tile M=128 pixels (half W-row), N=128; wave = 64x64 (4x4 MFMA 16x16x32).
template <int KC, int COUT, bool ACT>
__launch_bounds__(256)
__global__ void conv3x3_kernel(const short* __restrict__ in, const short* __restrict__ wt,
                               const float* __restrict__ bias, short* __restrict__ out) {
    __shared__ short lds[3 * 130 * 32];
    const int CIN_STR = KC * 32;
    int tile = blockIdx.x;
    int w0 = (tile & 1) << 7;
    int row = tile >> 1;              // b*128 + h
    int h = row & 127, b = row >> 7;
    int t = threadIdx.x;
    int lane = t & 63, wid = t >> 6;
    int wave_m = (wid & 1) << 6;      // 0 or 64 (pixel offset)
    int wave_n = (wid >> 1) << 6;     // 0 or 64 (cout offset)
    int q = lane >> 4, col = lane & 15;

    f32x4 acc[4][4] = {};

    for (int kc = 0; kc < KC; ++kc) {
        // ---- stage A-tile: 3 rows x 130 pixels x 32 ch (zero-padded at image borders) ----
        for (int ci = t; ci < 3 * 130 * 4; ci += 256) {
            int r = ci / 520;
            int rem = ci - r * 520;
            int p = rem >> 2, co = rem & 3;
            int gy = h + r - 1, gx = w0 + p - 1;
            short8 v = {};
            if ((unsigned)gy < 128u && (unsigned)gx < 256u)
                v = *(const short8*)(in + (size_t)((b * 128 + gy) * 256 + gx) * CIN_STR + kc * 32 + co * 8);
            *(short8*)(lds + (r * 130 + p) * 32 + co * 8) = v;
        }
        __syncthreads();

#pragma unroll
        for (int tap = 0; tap < 9; ++tap) {
            const int dy = tap / 3, dx = tap % 3;   // lds row dy, pixel shift dx (0..2 ~ -1..1)
            short8 a[4], bf[4];
#pragma unroll
            for (int mt = 0; mt < 4; ++mt) {
                int pix = wave_m + mt * 16 + col + dx;            // m = wave_m+mt*16+col
                a[mt] = *(const short8*)(lds + (dy * 130 + pix) * 32 + q * 8);
            }
            const short* wp = wt + ((size_t)(tap * KC + kc) << 12);
#pragma unroll
            for (int nt = 0; nt < 4; ++nt) {
                int n = wave_n + nt * 16 + col;
                bf[nt] = *(const short8*)(wp + n * 32 + q * 8);
            }
#pragma unroll
            for (int mt = 0; mt < 4; ++mt)
#pragma unroll
                for (int nt = 0; nt < 4; ++nt)
                    acc[mt][nt] = __builtin_amdgcn_mfma_f32_16x16x32_bf16(a[mt], bf[nt], acc[mt][nt], 0, 0, 0);
        }
        __syncthreads();
    }

    // ---- epilogue: D[m = wave_m+mt*16+q*4+r][n = wave_n+nt*16+col] ----
    size_t pixbase = (size_t)((b * 128 + h) * 256 + w0);
#pragma unroll
    for (int nt = 0; nt < 4; ++nt) {
        int n = wave_n + nt * 16 + col;
        if (n >= COUT) continue;
        float bv = bias[n];
#pragma unroll
        for (int mt = 0; mt < 4; ++mt) {
#pragma unroll
            for (int r = 0; r < 4; ++r) {
                int m = wave_m + mt * 16 + q * 4 + r;
                float v = acc[mt][nt][r] + bv;
                if (ACT) v = (v >= 0.f) ? v : LEAK * v;
                out[(pixbase + m) * COUT + n] = (short)f2b(v);
            }
        }
    }
}

// conv6: 3x3, Cin=32, Cout=1, linear, fp32 out
__global__ void conv6_kernel(const short* __restrict__ x, const float* __restrict__ k,
                             const float* __restrict__ bias, float* __restrict__ out) {
    __shared__ float wk[288];
    int t = threadIdx.x;
    for (int i = t; i < 288; i += 256) wk[i] = k[i];
    __syncthreads();
    int idx = blockIdx.x * 256 + t;
    int w = idx & 255, h = (idx >> 8) & 127, b = idx >> 15;
    float acc = bias[0];
#pragma unroll
    for (int dy = -1; dy <= 1; ++dy) {
        int gy = h + dy;
        if ((unsigned)gy >= 128u) continue;
#pragma unroll
        for (int dx = -1; dx <= 1; ++dx) {
            int gx = w + dx;
            if ((unsigned)gx >= 256u) continue;
            const short* xp = x + (size_t)((b * 128 + gy) * 256 + gx) * 32;
            const float* wp = wk + ((dy + 1) * 3 + (dx + 1)) * 32;
#pragma unroll
            for (int c = 0; c < 32; ++c) acc += b2f((unsigned short)xp[c]) * wp[c];
        }
    }
    out[idx] = acc;
}

extern "C" void kernel_launch(void* const* d_in, const int* in_sizes, int n_in,
                              void* d_out, int out_size, void* d_ws, size_t ws_size,
                              hipStream_t stream) {
    const float* left  = (const float*)d_in[0];
    const float* right = (const float*)d_in[1];
    const float* pd    = (const float*)d_in[2];
    const float* k[6];
    const float* bb[6];
    for (int i = 0; i < 6; ++i) { k[i] = (const float*)d_in[3 + 2 * i]; bb[i] = (const float*)d_in[4 + 2 * i]; }

    char* ws = (char*)d_ws;
    // region0 [0, 80MiB): vol -> X2 -> X4 ; region1 [80MiB, +64MiB): X1 -> X3 -> X5
    short* vol = (short*)ws;                               // 8*128*256*160*2 = 83,886,080 B
    short* X1  = (short*)(ws + 83886080);                  // 128ch, 64 MiB
    short* X2  = (short*)ws;                               // 128ch
    short* X3  = X1;                                       // 96ch (48 MiB <= 64 MiB)
    short* X4  = (short*)ws;                               // 64ch
    short* X5  = X1;                                       // 32ch
    short* wt1 = (short*)(ws + 150994944);
    short* wt2 = wt1 + 9 * 5 * 4096;
    short* wt3 = wt2 + 9 * 4 * 4096;
    short* wt4 = wt3 + 9 * 4 * 4096;
    short* wt5 = wt4 + 9 * 3 * 4096;

    prep_kernel<<<1024, 256, 0, stream>>>(left, right, pd, vol);
    wconv_kernel<<<(9 * 5 * 4096 + 255) / 256, 256, 0, stream>>>(k[0], wt1, 134, 128, 5);
    wconv_kernel<<<(9 * 4 * 4096 + 255) / 256, 256, 0, stream>>>(k[1], wt2, 128, 128, 4);
    wconv_kernel<<<(9 * 4 * 4096 + 255) / 256, 256, 0, stream>>>(k[2], wt3, 128, 96, 4);
    wconv_kernel<<<(9 * 3 * 4096 + 255) / 256, 256, 0, stream>>>(k[3], wt4, 96, 64, 3);
    wconv_kernel<<<(9 * 2 * 4096 + 255) / 256, 256, 0, stream>>>(k[4], wt5, 64, 32, 2);

    conv3x3_kernel<5, 128, true><<<2048, 256, 0, stream>>>(vol, wt1, bb[0], X1);
    conv3x3_kernel<4, 128, true><<<2048, 256, 0, stream>>>(X1, wt2, bb[1], X2);
    conv3x3_kernel<4,  96, true><<<2048, 256, 0, stream>>>(X2, wt3, bb[2], X3);
    conv3x3_kernel<3,  64, true><<<2048, 256, 0, stream>>>(X3, wt4, bb[3], X4);
    conv3x3_kernel<2,  32, true><<<2048, 256, 0, stream>>>(X4, wt5, bb[4], X5);
    conv6_kernel<<<1024, 256, 0, stream>>>(X5, k[5], bb[5], (float*)d_out);
}

// Round 3
// 807.496 us; speedup vs baseline: 1.1225x; 1.1225x over previous
//
#include <hip/hip_runtime.h>

typedef __attribute__((ext_vector_type(8))) short short8;
typedef __attribute__((ext_vector_type(4))) float f32x4;
typedef __attribute__((ext_vector_type(4))) unsigned short us4;

#define LEAK 0.2f

__device__ __forceinline__ float b2f(unsigned short s) {
    unsigned u = ((unsigned)s) << 16;
    return __builtin_bit_cast(float, u);
}
__device__ __forceinline__ unsigned short f2b(float f) {
    unsigned u = __builtin_bit_cast(unsigned, f);
    u += 0x7fffu + ((u >> 16) & 1u);
    return (unsigned short)(u >> 16);
}

// async 16B global->LDS (direct-to-shared DMA). LDS base wave-uniform; HW adds lane*16.
__device__ __forceinline__ void async16(const short* g, short* l) {
    __builtin_amdgcn_global_load_lds(
        (const __attribute__((address_space(1))) void*)g,
        (__attribute__((address_space(3))) void*)l, 16, 0, 0);
}

// ---------------- prep: upsample / warp / cost volume ----------------

__device__ __forceinline__ float up_at(const float* __restrict__ pd, int b, int i, int j) {
    float sy = i * 0.5f - 0.25f;
    float sx = j * 0.5f - 0.25f;
    float fy0 = floorf(sy), fx0 = floorf(sx);
    float fy = sy - fy0, fx = sx - fx0;
    int y0 = (int)fy0, x0 = (int)fx0;
    int y0c = min(max(y0, 0), 63), y1c = min(max(y0 + 1, 0), 63);
    int x0c = min(max(x0, 0), 127), x1c = min(max(x0 + 1, 0), 127);
    const float* p = pd + b * 64 * 128;
    float v00 = p[y0c * 128 + x0c], v01 = p[y0c * 128 + x1c];
    float v10 = p[y1c * 128 + x0c], v11 = p[y1c * 128 + x1c];
    return (1.f - fy) * ((1.f - fx) * v00 + fx * v01) + fy * ((1.f - fx) * v10 + fx * v11);
}

// faithful keras-bug warp: pixel-flat index into right.reshape(-1); cy integer
__device__ __forceinline__ float warp_at(const float* __restrict__ right,
                                         const float* __restrict__ pd, int b, int i, int j) {
    float up = up_at(pd, b, i, j);
    float cx = (float)j - up;
    float x0 = floorf(cx), x1 = x0 + 1.f;
    float w0 = x1 - cx, w1 = cx - x0;
    float x0s = fminf(fmaxf(x0, 0.f), 255.f);
    float x1s = fminf(fmaxf(x1, 0.f), 255.f);
    float base = (float)(b * 32768 + i * 256);
    int i0 = (int)(x0s + base);
    int i1 = (int)(x1s + base);
    return w0 * right[i0] + w1 * right[i1];
}

// vol: halo layout [B,130,258,144] bf16. Interior pixel (h,w) -> row h+1, col w+1.
// ch 0..127 = left, 128..132 = costs, 133 = up, 134..143 = 0.
__global__ void prep_kernel(const float* __restrict__ left, const float* __restrict__ right,
                            const float* __restrict__ pd, short* __restrict__ vol) {
    int idx = blockIdx.x * 256 + threadIdx.x;
    int w = idx & 255, h = (idx >> 8) & 127, b = idx >> 15;
    const float* lp = left + (size_t)idx * 128;
    short* vp = vol + ((size_t)(b * 130 + h + 1) * 258 + (w + 1)) * 144;
    float sum = 0.f;
#pragma unroll 8
    for (int c = 0; c < 128; c += 4) {
        float4 v = *(const float4*)(lp + c);
        sum += (v.x + v.y) + (v.z + v.w);
        us4 o;
        o.x = f2b(v.x); o.y = f2b(v.y); o.z = f2b(v.z); o.w = f2b(v.w);
        *(us4*)(vp + c) = o;
    }
    float meanleft = sum * (1.f / 128.f);
    float up = up_at(pd, b, h, w);
#pragma unroll
    for (int t = 0; t < 5; ++t) {
        int jj = w + t - 2;
        float cost = 0.f;
        if (jj >= 0 && jj < 256) cost = warp_at(right, pd, b, h, jj) * meanleft;
        vp[128 + t] = (short)f2b(cost);
    }
    vp[133] = (short)f2b(up);
#pragma unroll
    for (int c = 134; c < 144; c += 2) { vp[c] = 0; vp[c + 1] = 0; }
}

// zero the halo ring (rows 0,129 full; cols 0,257 rows 1..128) of ONE buffer.
// Must be scheduled AFTER the last reader of any aliased previous-layout buffer.
__global__ void halo_zero_one(short* __restrict__ buf, int C) {
    int nchunk = C >> 3;
    int slot = blockIdx.x * 256 + threadIdx.x;
    int total = 8 * 772 * nchunk;
    if (slot >= total) return;
    int chunk = slot % nchunk;
    int pix = slot / nchunk;                 // 0..6175
    int b = pix / 772, p = pix % 772;
    int row, col;
    if (p < 516) { row = (p < 258) ? 0 : 129; col = (p < 258) ? p : p - 258; }
    else { int q = p - 516; row = 1 + (q >> 1); col = (q & 1) ? 257 : 0; }
    short8 z = {};
    *(short8*)(buf + ((size_t)(b * 130 + row) * 258 + col) * C + chunk * 8) = z;
}

// fp32 HWIO weights -> bf16 [tap][kc][n(COUT)][k(32)], k zero-padded
__global__ void wconv_kernel(const float* __restrict__ k, short* __restrict__ wt,
                             int CIN, int COUT, int KC) {
    int idx = blockIdx.x * 256 + threadIdx.x;
    int total = 9 * KC * COUT * 32;
    if (idx >= total) return;
    int kk = idx & 31;
    int rest = idx >> 5;
    int n = rest % COUT; rest /= COUT;
    int kc = rest % KC, tap = rest / KC;
    int ci = kc * 32 + kk;
    float v = (ci < CIN) ? k[(size_t)(tap * CIN + ci) * COUT + n] : 0.f;
    wt[idx] = (short)f2b(v);
}

// 3x3 SAME conv over halo layout [B,130,258,CIN_STR] -> halo layout [B,130,258,COUT].
// Block: 256 thr = 4 waves, tile M=256 px (2 rows x 128 cols), wave = 64m x COUT n.
// Per 32-ch K chunk: stage 4 rows x 130 px x 32ch into LDS via global_load_lds,
// XOR-swizzled (chunk c at slot (p+c)&3) to kill bank conflicts. LASTC<4 masks a
// half chunk (stale LDS is finite bf16 from previous kc; weights there are zero).
template <int KC, int CIN_STR, int COUT, int NT, int LASTC>
__launch_bounds__(256, 2)
__global__ void conv3x3_kernel(const short* __restrict__ in, const short* __restrict__ wt,
                               const float* __restrict__ bias, short* __restrict__ out) {
    __shared__ short lds[2080 * 8];          // 4 rows * 130 px * 4 chunks * 16B = 33,280 B
    int t = threadIdx.x;
    int lane = t & 63, wid = t >> 6;
    int q = lane >> 4, col = lane & 15;
    int out_row = wid >> 1, col_off = (wid & 1) << 6;

    int wtile = blockIdx.x & 1;
    int rest = blockIdx.x >> 1;
    int htile = rest & 63, b = rest >> 6;
    int w0h = wtile << 7;                    // staged col range w0h .. w0h+129
    int row0 = htile << 1;                   // staged rows row0 .. row0+3

    const short* inbase = in + ((size_t)(b * 130 + row0) * 258 + w0h) * CIN_STR;

    f32x4 acc[4][NT] = {};

    for (int kc = 0; kc < KC; ++kc) {
        // ---- stage: 2080 slots of 16B; LDS slot i <- global chunk c=(s-p)&3 ----
        for (int i = t; i < 2080; i += 256) {
            int r = i / 520, rem = i % 520;
            int p = rem >> 2, s = rem & 3;
            int c = (s - p) & 3;
            if (kc < KC - 1 || c < LASTC) {
                const short* g = inbase + ((size_t)r * 258 + p) * CIN_STR + kc * 32 + c * 8;
                async16(g, lds + (size_t)((i >> 6) << 6) * 8);
            }
        }
        __syncthreads();

        const short* wl = wt + (size_t)kc * COUT * 32;
#pragma unroll
        for (int dy = 0; dy < 3; ++dy) {
#pragma unroll
            for (int dx = 0; dx < 3; ++dx) {
                int ldsrow = out_row + dy;
                short8 a[4], bfr[NT];
#pragma unroll
                for (int mt = 0; mt < 4; ++mt) {
                    int p = col_off + mt * 16 + col + dx;
                    a[mt] = *(const short8*)(lds +
                        (size_t)(((ldsrow * 130 + p) << 2) + ((q + p) & 3)) * 8);
                }
                const short* wp = wl + (size_t)(dy * 3 + dx) * KC * COUT * 32;
#pragma unroll
                for (int nt = 0; nt < NT; ++nt)
                    bfr[nt] = *(const short8*)(wp + (nt * 16 + col) * 32 + q * 8);
#pragma unroll
                for (int mt = 0; mt < 4; ++mt)
#pragma unroll
                    for (int nt = 0; nt < NT; ++nt)
                        acc[mt][nt] = __builtin_amdgcn_mfma_f32_16x16x32_bf16(
                            a[mt], bfr[nt], acc[mt][nt], 0, 0, 0);
            }
        }
        __syncthreads();
    }

    // ---- epilogue: D[m = mt*16 + q*4 + rr][n = nt*16 + col], leaky-relu, bf16 ----
    size_t obase = ((size_t)(b * 130 + row0 + 1 + out_row) * 258 + (w0h + 1 + col_off)) * COUT;
#pragma unroll
    for (int nt = 0; nt < NT; ++nt) {
        int n = nt * 16 + col;
        float bv = bias[n];
#pragma unroll
        for (int mt = 0; mt < 4; ++mt) {
#pragma unroll
            for (int rr = 0; rr < 4; ++rr) {
                int m = mt * 16 + q * 4 + rr;
                float v = acc[mt][nt][rr] + bv;
                v = (v >= 0.f) ? v : LEAK * v;
                out[obase + (size_t)m * COUT + n] = (short)f2b(v);
            }
        }
    }
}

// conv6: 3x3, Cin=32 (halo layout), Cout=1, linear, fp32 out (flat [B,H,W])
__global__ void conv6_kernel(const short* __restrict__ x, const float* __restrict__ k,
                             const float* __restrict__ bias, float* __restrict__ out) {
    __shared__ float wk[288];
    int t = threadIdx.x;
    for (int i = t; i < 288; i += 256) wk[i] = k[i];
    __syncthreads();
    int idx = blockIdx.x * 256 + t;
    int w = idx & 255, h = (idx >> 8) & 127, b = idx >> 15;
    float acc = bias[0];
#pragma unroll
    for (int dy = 0; dy < 3; ++dy) {
#pragma unroll
        for (int dx = 0; dx < 3; ++dx) {
            const short* xp = x + ((size_t)(b * 130 + h + dy) * 258 + (w + dx)) * 32;
            const float* wp = wk + (dy * 3 + dx) * 32;
#pragma unroll
            for (int c8 = 0; c8 < 4; ++c8) {
                short8 v = *(const short8*)(xp + c8 * 8);
#pragma unroll
                for (int j = 0; j < 8; ++j)
                    acc += b2f((unsigned short)v[j]) * wp[c8 * 8 + j];
            }
        }
    }
    out[idx] = acc;
}

extern "C" void kernel_launch(void* const* d_in, const int* in_sizes, int n_in,
                              void* d_out, int out_size, void* d_ws, size_t ws_size,
                              hipStream_t stream) {
    const float* left  = (const float*)d_in[0];
    const float* right = (const float*)d_in[1];
    const float* pd    = (const float*)d_in[2];
    const float* k[6];
    const float* bb[6];
    for (int i = 0; i < 6; ++i) { k[i] = (const float*)d_in[3 + 2 * i]; bb[i] = (const float*)d_in[4 + 2 * i]; }

    char* ws = (char*)d_ws;
    // weights: [0, 1 MiB)
    short* wt1 = (short*)ws;                       // 9*5*128*32 = 184320 sh (368,640 B)
    short* wt2 = (short*)(ws + 368640);            // 9*4*128*32 = 147456 sh (294,912 B)
    short* wt3 = (short*)(ws + 663552);            // 9*4*96*32  = 110592 sh (221,184 B)
    short* wt4 = (short*)(ws + 884736);            // 9*3*64*32  =  55296 sh (110,592 B)
    short* wt5 = (short*)(ws + 995328);            // 9*2*32*32  =  18432 sh ( 36,864 B)
    // region A @1 MiB: vol(C=144) -> X2(128) -> X4(64); region B: X1(128) -> X3(96) -> X5(32)
    short* vol = (short*)(ws + 1048576);
    short* X1  = (short*)(ws + 1048576 + 77276160);
    short* X2  = vol;
    short* X3  = X1;
    short* X4  = vol;
    short* X5  = X1;

    auto hz = [&](short* buf, int C) {
        int blocks = (8 * 772 * (C >> 3) + 255) / 256;
        halo_zero_one<<<blocks, 256, 0, stream>>>(buf, C);
    };

    prep_kernel<<<1024, 256, 0, stream>>>(left, right, pd, vol);
    wconv_kernel<<<720, 256, 0, stream>>>(k[0], wt1, 134, 128, 5);
    wconv_kernel<<<576, 256, 0, stream>>>(k[1], wt2, 128, 128, 4);
    wconv_kernel<<<432, 256, 0, stream>>>(k[2], wt3, 128, 96, 4);
    wconv_kernel<<<216, 256, 0, stream>>>(k[3], wt4, 96, 64, 3);
    wconv_kernel<<<72,  256, 0, stream>>>(k[4], wt5, 64, 32, 2);
    // regions fresh from poison: vol (A, 144-layout) and X1 (B, 128-layout) halos now.
    hz(vol, 144);
    hz(X1, 128);

    conv3x3_kernel<5, 144, 128, 8, 2><<<1024, 256, 0, stream>>>(vol, wt1, bb[0], X1);
    hz(X2, 128);   // region A: safe only after conv1 finished reading vol
    conv3x3_kernel<4, 128, 128, 8, 4><<<1024, 256, 0, stream>>>(X1, wt2, bb[1], X2);
    hz(X3, 96);    // region B: safe only after conv2 finished reading X1
    conv3x3_kernel<4, 128,  96, 6, 4><<<1024, 256, 0, stream>>>(X2, wt3, bb[2], X3);
    hz(X4, 64);    // region A: safe only after conv3 finished reading X2
    conv3x3_kernel<3,  96,  64, 4, 4><<<1024, 256, 0, stream>>>(X3, wt4, bb[3], X4);
    hz(X5, 32);    // region B: safe only after conv4 finished reading X3
    conv3x3_kernel<2,  64,  32, 2, 4><<<1024, 256, 0, stream>>>(X4, wt5, bb[4], X5);
    conv6_kernel<<<1024, 256, 0, stream>>>(X5, k[5], bb[5], (float*)d_out);
}

// Round 4
// 697.075 us; speedup vs baseline: 1.3003x; 1.1584x over previous
//
#include <hip/hip_runtime.h>

typedef __attribute__((ext_vector_type(8))) short short8;
typedef __attribute__((ext_vector_type(4))) float f32x4;
typedef __attribute__((ext_vector_type(4))) unsigned short us4;

#define LEAK 0.2f

__device__ __forceinline__ float b2f(unsigned short s) {
    unsigned u = ((unsigned)s) << 16;
    return __builtin_bit_cast(float, u);
}
__device__ __forceinline__ unsigned short f2b(float f) {
    unsigned u = __builtin_bit_cast(unsigned, f);
    u += 0x7fffu + ((u >> 16) & 1u);
    return (unsigned short)(u >> 16);
}

// async 16B global->LDS (direct-to-shared DMA). LDS base wave-uniform; HW adds lane*16.
__device__ __forceinline__ void async16(const short* g, short* l) {
    __builtin_amdgcn_global_load_lds(
        (const __attribute__((address_space(1))) void*)g,
        (__attribute__((address_space(3))) void*)l, 16, 0, 0);
}

// ---------------- prep: upsample / warp / cost volume ----------------

__device__ __forceinline__ float up_at(const float* __restrict__ pd, int b, int i, int j) {
    float sy = i * 0.5f - 0.25f;
    float sx = j * 0.5f - 0.25f;
    float fy0 = floorf(sy), fx0 = floorf(sx);
    float fy = sy - fy0, fx = sx - fx0;
    int y0 = (int)fy0, x0 = (int)fx0;
    int y0c = min(max(y0, 0), 63), y1c = min(max(y0 + 1, 0), 63);
    int x0c = min(max(x0, 0), 127), x1c = min(max(x0 + 1, 0), 127);
    const float* p = pd + b * 64 * 128;
    float v00 = p[y0c * 128 + x0c], v01 = p[y0c * 128 + x1c];
    float v10 = p[y1c * 128 + x0c], v11 = p[y1c * 128 + x1c];
    return (1.f - fy) * ((1.f - fx) * v00 + fx * v01) + fy * ((1.f - fx) * v10 + fx * v11);
}

// faithful keras-bug warp: pixel-flat index into right.reshape(-1); cy integer
__device__ __forceinline__ float warp_at(const float* __restrict__ right,
                                         const float* __restrict__ pd, int b, int i, int j) {
    float up = up_at(pd, b, i, j);
    float cx = (float)j - up;
    float x0 = floorf(cx), x1 = x0 + 1.f;
    float w0 = x1 - cx, w1 = cx - x0;
    float x0s = fminf(fmaxf(x0, 0.f), 255.f);
    float x1s = fminf(fmaxf(x1, 0.f), 255.f);
    float base = (float)(b * 32768 + i * 256);
    int i0 = (int)(x0s + base);
    int i1 = (int)(x1s + base);
    return w0 * right[i0] + w1 * right[i1];
}

// vol: halo layout [B,130,258,144] bf16. Interior pixel (h,w) -> row h+1, col w+1.
__global__ void prep_kernel(const float* __restrict__ left, const float* __restrict__ right,
                            const float* __restrict__ pd, short* __restrict__ vol) {
    int idx = blockIdx.x * 256 + threadIdx.x;
    int w = idx & 255, h = (idx >> 8) & 127, b = idx >> 15;
    const float* lp = left + (size_t)idx * 128;
    short* vp = vol + ((size_t)(b * 130 + h + 1) * 258 + (w + 1)) * 144;
    float sum = 0.f;
#pragma unroll 8
    for (int c = 0; c < 128; c += 4) {
        float4 v = *(const float4*)(lp + c);
        sum += (v.x + v.y) + (v.z + v.w);
        us4 o;
        o.x = f2b(v.x); o.y = f2b(v.y); o.z = f2b(v.z); o.w = f2b(v.w);
        *(us4*)(vp + c) = o;
    }
    float meanleft = sum * (1.f / 128.f);
    float up = up_at(pd, b, h, w);
#pragma unroll
    for (int t = 0; t < 5; ++t) {
        int jj = w + t - 2;
        float cost = 0.f;
        if (jj >= 0 && jj < 256) cost = warp_at(right, pd, b, h, jj) * meanleft;
        vp[128 + t] = (short)f2b(cost);
    }
    vp[133] = (short)f2b(up);
#pragma unroll
    for (int c = 134; c < 144; c += 2) { vp[c] = 0; vp[c + 1] = 0; }
}

// zero the halo ring of ONE buffer (schedule AFTER last reader of aliased layout)
__global__ void halo_zero_one(short* __restrict__ buf, int C) {
    int nchunk = C >> 3;
    int slot = blockIdx.x * 256 + threadIdx.x;
    int total = 8 * 772 * nchunk;
    if (slot >= total) return;
    int chunk = slot % nchunk;
    int pix = slot / nchunk;
    int b = pix / 772, p = pix % 772;
    int row, col;
    if (p < 516) { row = (p < 258) ? 0 : 129; col = (p < 258) ? p : p - 258; }
    else { int q = p - 516; row = 1 + (q >> 1); col = (q & 1) ? 257 : 0; }
    short8 z = {};
    *(short8*)(buf + ((size_t)(b * 130 + row) * 258 + col) * C + chunk * 8) = z;
}

// fp32 HWIO weights -> bf16 [kc][tap][n][k(32)], k zero-padded (per-kc slice contiguous)
__global__ void wconv_kernel(const float* __restrict__ k, short* __restrict__ wt,
                             int CIN, int COUT, int KC) {
    int idx = blockIdx.x * 256 + threadIdx.x;
    int total = 9 * KC * COUT * 32;
    if (idx >= total) return;
    int kk = idx & 31;
    int rest = idx >> 5;
    int n = rest % COUT; rest /= COUT;
    int tap = rest % 9, kc = rest / 9;
    int ci = kc * 32 + kk;
    float v = (ci < CIN) ? k[(size_t)(tap * CIN + ci) * COUT + n] : 0.f;
    wt[idx] = (short)f2b(v);
}

// 3x3 SAME conv, halo layout [B,130,258,CIN_STR] -> [B,130,258,COUT].
// Block: 512 thr = 8 waves; tile M=512 px (4 rows x 128 cols); wave = 64m x COUT n.
// Per 32-ch K chunk: async-stage A (6 rows x 130 px, XOR-swizzled) AND the kc's
// full weight slice [9][COUT][32] into LDS; compute phase is pure LDS + MFMA.
template <int KC, int CIN_STR, int COUT, int NT, int LASTC>
__launch_bounds__(512, 2)
__global__ void conv3x3_kernel(const short* __restrict__ in, const short* __restrict__ wt,
                               const float* __restrict__ bias, short* __restrict__ out) {
    __shared__ short ldsA[6 * 130 * 4 * 8];      // 49,920 B
    __shared__ short ldsW[9 * COUT * 32];        // COUT=128: 73,728 B
    const int WSLOTS = 9 * COUT * 4;             // 16B granules in the W slice
    const int WSTRIDE = 9 * COUT * 32;           // shorts per kc slice

    int t = threadIdx.x;
    int lane = t & 63, wid = t >> 6;
    int q = lane >> 4, col = lane & 15;
    int out_row = wid >> 1, col_off = (wid & 1) << 6;

    int wtile = blockIdx.x & 1;
    int rest = blockIdx.x >> 1;
    int htile = rest & 31, b = rest >> 5;
    int w0h = wtile << 7;                        // staged col range w0h .. w0h+129
    int row0 = htile << 2;                       // staged rows row0 .. row0+5

    const short* inbase = in + ((size_t)(b * 130 + row0) * 258 + w0h) * CIN_STR;

    f32x4 acc[4][NT] = {};

    for (int kc = 0; kc < KC; ++kc) {
        // ---- stage A: 3120 granules (r*520 + p*4 + s), chunk c=(s-p)&3 ----
        for (int i = t; i < 3120; i += 512) {
            int r = i / 520, rem = i % 520;
            int p = rem >> 2, s = rem & 3;
            int c = (s - p) & 3;
            if (LASTC == 4 || kc < KC - 1 || c < LASTC) {
                const short* g = inbase + ((size_t)r * 258 + p) * CIN_STR + kc * 32 + c * 8;
                async16(g, ldsA + (size_t)(i & ~63) * 8);
            }
        }
        // ---- stage W: identity copy of the kc slice ----
        {
            const short* wsrc = wt + (size_t)kc * WSTRIDE;
            for (int i = t; i < WSLOTS; i += 512)
                async16(wsrc + (size_t)i * 8, ldsW + (size_t)(i & ~63) * 8);
        }
        __syncthreads();

#pragma unroll
        for (int dy = 0; dy < 3; ++dy) {
#pragma unroll
            for (int dx = 0; dx < 3; ++dx) {
                int ldsrow = out_row + dy;
                short8 a[4], bfr[NT];
#pragma unroll
                for (int mt = 0; mt < 4; ++mt) {
                    int p = col_off + mt * 16 + col + dx;
                    a[mt] = *(const short8*)(ldsA +
                        (size_t)(((ldsrow * 130 + p) << 2) + ((q + p) & 3)) * 8);
                }
                const short* wp = ldsW + (size_t)(dy * 3 + dx) * COUT * 32;
#pragma unroll
                for (int nt = 0; nt < NT; ++nt)
                    bfr[nt] = *(const short8*)(wp + (nt * 16 + col) * 32 + q * 8);
#pragma unroll
                for (int mt = 0; mt < 4; ++mt)
#pragma unroll
                    for (int nt = 0; nt < NT; ++nt)
                        acc[mt][nt] = __builtin_amdgcn_mfma_f32_16x16x32_bf16(
                            a[mt], bfr[nt], acc[mt][nt], 0, 0, 0);
            }
        }
        __syncthreads();
    }

    // ---- epilogue: D[m = mt*16 + q*4 + rr][n = nt*16 + col], leaky-relu, bf16 ----
    size_t obase = ((size_t)(b * 130 + row0 + 1 + out_row) * 258 + (w0h + 1 + col_off)) * COUT;
#pragma unroll
    for (int nt = 0; nt < NT; ++nt) {
        int n = nt * 16 + col;
        float bv = bias[n];
#pragma unroll
        for (int mt = 0; mt < 4; ++mt) {
#pragma unroll
            for (int rr = 0; rr < 4; ++rr) {
                int m = mt * 16 + q * 4 + rr;
                float v = acc[mt][nt][rr] + bv;
                v = (v >= 0.f) ? v : LEAK * v;
                out[obase + (size_t)m * COUT + n] = (short)f2b(v);
            }
        }
    }
}

// conv6: 3x3, Cin=32 (halo layout), Cout=1, linear, fp32 out (flat [B,H,W])
__global__ void conv6_kernel(const short* __restrict__ x, const float* __restrict__ k,
                             const float* __restrict__ bias, float* __restrict__ out) {
    __shared__ float wk[288];
    int t = threadIdx.x;
    for (int i = t; i < 288; i += 256) wk[i] = k[i];
    __syncthreads();
    int idx = blockIdx.x * 256 + t;
    int w = idx & 255, h = (idx >> 8) & 127, b = idx >> 15;
    float acc = bias[0];
#pragma unroll
    for (int dy = 0; dy < 3; ++dy) {
#pragma unroll
        for (int dx = 0; dx < 3; ++dx) {
            const short* xp = x + ((size_t)(b * 130 + h + dy) * 258 + (w + dx)) * 32;
            const float* wp = wk + (dy * 3 + dx) * 32;
#pragma unroll
            for (int c8 = 0; c8 < 4; ++c8) {
                short8 v = *(const short8*)(xp + c8 * 8);
#pragma unroll
                for (int j = 0; j < 8; ++j)
                    acc += b2f((unsigned short)v[j]) * wp[c8 * 8 + j];
            }
        }
    }
    out[idx] = acc;
}

extern "C" void kernel_launch(void* const* d_in, const int* in_sizes, int n_in,
                              void* d_out, int out_size, void* d_ws, size_t ws_size,
                              hipStream_t stream) {
    const float* left  = (const float*)d_in[0];
    const float* right = (const float*)d_in[1];
    const float* pd    = (const float*)d_in[2];
    const float* k[6];
    const float* bb[6];
    for (int i = 0; i < 6; ++i) { k[i] = (const float*)d_in[3 + 2 * i]; bb[i] = (const float*)d_in[4 + 2 * i]; }

    char* ws = (char*)d_ws;
    // weights: [0, 1 MiB)
    short* wt1 = (short*)ws;                       // 9*5*128*32 shorts
    short* wt2 = (short*)(ws + 368640);
    short* wt3 = (short*)(ws + 663552);
    short* wt4 = (short*)(ws + 884736);
    short* wt5 = (short*)(ws + 995328);
    // region A @1 MiB: vol(C=144) -> X2(128) -> X4(64); region B: X1(128) -> X3(96) -> X5(32)
    short* vol = (short*)(ws + 1048576);
    short* X1  = (short*)(ws + 1048576 + 77276160);
    short* X2  = vol;
    short* X3  = X1;
    short* X4  = vol;
    short* X5  = X1;

    auto hz = [&](short* buf, int C) {
        int blocks = (8 * 772 * (C >> 3) + 255) / 256;
        halo_zero_one<<<blocks, 256, 0, stream>>>(buf, C);
    };

    prep_kernel<<<1024, 256, 0, stream>>>(left, right, pd, vol);
    wconv_kernel<<<720, 256, 0, stream>>>(k[0], wt1, 134, 128, 5);
    wconv_kernel<<<576, 256, 0, stream>>>(k[1], wt2, 128, 128, 4);
    wconv_kernel<<<432, 256, 0, stream>>>(k[2], wt3, 128, 96, 4);
    wconv_kernel<<<216, 256, 0, stream>>>(k[3], wt4, 96, 64, 3);
    wconv_kernel<<<72,  256, 0, stream>>>(k[4], wt5, 64, 32, 2);
    hz(vol, 144);
    hz(X1, 128);

    conv3x3_kernel<5, 144, 128, 8, 2><<<512, 512, 0, stream>>>(vol, wt1, bb[0], X1);
    hz(X2, 128);   // region A: only after conv1 finished reading vol
    conv3x3_kernel<4, 128, 128, 8, 4><<<512, 512, 0, stream>>>(X1, wt2, bb[1], X2);
    hz(X3, 96);    // region B: only after conv2 finished reading X1
    conv3x3_kernel<4, 128,  96, 6, 4><<<512, 512, 0, stream>>>(X2, wt3, bb[2], X3);
    hz(X4, 64);    // region A: only after conv3 finished reading X2
    conv3x3_kernel<3,  96,  64, 4, 4><<<512, 512, 0, stream>>>(X3, wt4, bb[3], X4);
    hz(X5, 32);    // region B: only after conv4 finished reading X3
    conv3x3_kernel<2,  64,  32, 2, 4><<<512, 512, 0, stream>>>(X4, wt5, bb[4], X5);
    conv6_kernel<<<1024, 256, 0, stream>>>(X5, k[5], bb[5], (float*)d_out);
}

// Round 5
// 628.202 us; speedup vs baseline: 1.4429x; 1.1096x over previous
//
#include <hip/hip_runtime.h>

typedef __attribute__((ext_vector_type(8))) short short8;
typedef __attribute__((ext_vector_type(4))) float f32x4;
typedef __attribute__((ext_vector_type(4))) unsigned short us4;

#define LEAK 0.2f

__device__ __forceinline__ float b2f(unsigned short s) {
    unsigned u = ((unsigned)s) << 16;
    return __builtin_bit_cast(float, u);
}
__device__ __forceinline__ unsigned short f2b(float f) {
    unsigned u = __builtin_bit_cast(unsigned, f);
    u += 0x7fffu + ((u >> 16) & 1u);
    return (unsigned short)(u >> 16);
}

// async 16B global->LDS (direct-to-shared DMA). LDS base wave-uniform; HW adds lane*16.
__device__ __forceinline__ void async16(const short* g, short* l) {
    __builtin_amdgcn_global_load_lds(
        (const __attribute__((address_space(1))) void*)g,
        (__attribute__((address_space(3))) void*)l, 16, 0, 0);
}

// ---------------- prep: upsample / warp / cost volume (LDS-staged, coalesced) ----
// Block = 64 pixels of one row (quarter row). All global I/O is 16B/lane contiguous.
// vol: halo layout [B,130,258,144] bf16; interior pixel (h,w) -> row h+1, col w+1.
// ch 0..127 = left(bf16), 128..132 = costs, 133 = up, 134..143 = 0.
__global__ __launch_bounds__(256)
void prep_kernel(const float* __restrict__ left, const float* __restrict__ right,
                 const float* __restrict__ pd, short* __restrict__ vol) {
    __shared__ __align__(16) float inL[64 * 132];   // [px][128 ch + 4 pad]
    __shared__ __align__(16) float rrow[256];       // right row (b,h)
    __shared__ __align__(16) float pr0[128];        // pd row y0c
    __shared__ __align__(16) float pr1[128];        // pd row y1c
    __shared__ __align__(16) short outT[64 * 144];  // output tile

    int t = threadIdx.x;
    int blk = blockIdx.x;                 // 4096 = b(8) * h(128) * wq(4)
    int wq = blk & 3, h = (blk >> 2) & 127, b = blk >> 9;
    int w0 = wq << 6;

    // row-uniform upsample y terms
    float sy = h * 0.5f - 0.25f;
    float fy0 = floorf(sy);
    float fy = sy - fy0;
    int y0 = (int)fy0;
    int y0c = min(max(y0, 0), 63), y1c = min(max(y0 + 1, 0), 63);

    // ---- phase 1: coalesced loads -> LDS ----
    const float* lp = left + ((size_t)((b * 128 + h) * 256 + w0)) * 128;
#pragma unroll
    for (int k2 = 0; k2 < 8; ++k2) {
        int g = t + k2 * 256;             // granule 0..2047 (16B each)
        int p = g >> 5, j = g & 31;
        float4 v = *(const float4*)(lp + (size_t)g * 4);
        *(float4*)(&inL[p * 132 + j * 4]) = v;
    }
    if (t < 64) {
        *(float4*)(&rrow[t * 4]) =
            *(const float4*)(right + ((size_t)(b * 128 + h)) * 256 + t * 4);
    } else if (t < 96) {
        int i2 = t - 64;
        *(float4*)(&pr0[i2 * 4]) = *(const float4*)(pd + (size_t)(b * 64 + y0c) * 128 + i2 * 4);
    } else if (t < 128) {
        int i2 = t - 96;
        *(float4*)(&pr1[i2 * 4]) = *(const float4*)(pd + (size_t)(b * 64 + y1c) * 128 + i2 * 4);
    }
    __syncthreads();

    // ---- phase 2: 4 threads per pixel ----
    int p = t >> 2, s = t & 3;
    int w = w0 + p;
    const float* src = &inL[p * 132 + s * 32];
    short* odst = &outT[p * 144 + s * 32];
    float sum = 0.f;
#pragma unroll
    for (int i = 0; i < 8; ++i) {
        float f0 = src[i * 4], f1 = src[i * 4 + 1], f2 = src[i * 4 + 2], f3 = src[i * 4 + 3];
        sum += (f0 + f1) + (f2 + f3);
        us4 o;
        o.x = f2b(f0); o.y = f2b(f1); o.z = f2b(f2); o.w = f2b(f3);
        *(us4*)(odst + i * 4) = o;
    }
    sum += __shfl_xor(sum, 1);
    sum += __shfl_xor(sum, 2);
    float mean = sum * (1.f / 128.f);

    float one_fy = 1.f - fy;
#pragma unroll
    for (int tap = s; tap < 5; tap += 4) {   // s=0 -> taps 0,4; s=1,2,3 -> taps 1,2,3
        int jj = w + tap - 2;
        if (jj >= 0 && jj < 256) {
            float sx = jj * 0.5f - 0.25f;
            float fx0 = floorf(sx);
            float fx = sx - fx0;
            int x0 = (int)fx0;
            int x0c = min(max(x0, 0), 127), x1c = min(max(x0 + 1, 0), 127);
            float up = one_fy * ((1.f - fx) * pr0[x0c] + fx * pr0[x1c])
                     + fy     * ((1.f - fx) * pr1[x0c] + fx * pr1[x1c]);
            float cx = (float)jj - up;
            float xf0 = floorf(cx), xf1 = xf0 + 1.f;
            float w0x = xf1 - cx, w1x = cx - xf0;
            int ix0 = (int)fminf(fmaxf(xf0, 0.f), 255.f);
            int ix1 = (int)fminf(fmaxf(xf1, 0.f), 255.f);
            float warped = w0x * rrow[ix0] + w1x * rrow[ix1];
            outT[p * 144 + 128 + tap] = (short)f2b(warped * mean);
            if (tap == 2) outT[p * 144 + 133] = (short)f2b(up);   // jj==w always in-range
        } else {
            outT[p * 144 + 128 + tap] = 0;
        }
    }
    if (s == 0) { outT[p * 144 + 134] = 0; outT[p * 144 + 135] = 0; }
    if (s == 3) {
        us4 z = {};
        *(us4*)(&outT[p * 144 + 136]) = z;
        *(us4*)(&outT[p * 144 + 140]) = z;
    }
    __syncthreads();

    // ---- phase 3: coalesced store (tile is contiguous in halo layout) ----
    short* gdst = vol + ((size_t)(b * 130 + h + 1) * 258 + (w0 + 1)) * 144;
    for (int g = t; g < 1152; g += 256)
        *(short8*)(gdst + g * 8) = *(const short8*)(&outT[g * 8]);
}

// zero the halo ring of ONE buffer (schedule AFTER last reader of aliased layout)
__global__ void halo_zero_one(short* __restrict__ buf, int C) {
    int nchunk = C >> 3;
    int slot = blockIdx.x * 256 + threadIdx.x;
    int total = 8 * 772 * nchunk;
    if (slot >= total) return;
    int chunk = slot % nchunk;
    int pix = slot / nchunk;
    int b = pix / 772, p = pix % 772;
    int row, col;
    if (p < 516) { row = (p < 258) ? 0 : 129; col = (p < 258) ? p : p - 258; }
    else { int q = p - 516; row = 1 + (q >> 1); col = (q & 1) ? 257 : 0; }
    short8 z = {};
    *(short8*)(buf + ((size_t)(b * 130 + row) * 258 + col) * C + chunk * 8) = z;
}

// fp32 HWIO weights -> bf16 [kc][tap][n][k(32)], k zero-padded; all 5 layers in one launch
__global__ void wconv_all(const float* __restrict__ k1, const float* __restrict__ k2,
                          const float* __restrict__ k3, const float* __restrict__ k4,
                          const float* __restrict__ k5,
                          short* __restrict__ w1, short* __restrict__ w2,
                          short* __restrict__ w3, short* __restrict__ w4,
                          short* __restrict__ w5) {
    const int CINt[5]  = {134, 128, 128, 96, 64};
    const int COUTt[5] = {128, 128, 96, 64, 32};
    const int KCt[5]   = {5, 4, 4, 3, 2};
    const float* srcs[5] = {k1, k2, k3, k4, k5};
    short* dsts[5] = {w1, w2, w3, w4, w5};
    int l = blockIdx.y;
    int CIN = CINt[l], COUT = COUTt[l], KC = KCt[l];
    const float* k = srcs[l];
    short* wt = dsts[l];
    int idx = blockIdx.x * 256 + threadIdx.x;
    int total = 9 * KC * COUT * 32;
    if (idx >= total) return;
    int kk = idx & 31;
    int rest = idx >> 5;
    int n = rest % COUT; rest /= COUT;
    int tap = rest % 9, kc = rest / 9;
    int ci = kc * 32 + kk;
    float v = (ci < CIN) ? k[(size_t)(tap * CIN + ci) * COUT + n] : 0.f;
    wt[idx] = (short)f2b(v);
}

// 3x3 SAME conv, halo layout [B,130,258,CIN_STR] -> [B,130,258,COUT].
// Block: 512 thr = 8 waves; tile M=512 px (4 rows x 128 cols); wave = 64m x COUT n.
// Per 32-ch K chunk: async-stage A (6 rows x 130 px, XOR-swizzled) AND the kc's
// full weight slice [9][COUT][32] into LDS; compute phase is pure LDS + MFMA.
template <int KC, int CIN_STR, int COUT, int NT, int LASTC>
__launch_bounds__(512, 2)
__global__ void conv3x3_kernel(const short* __restrict__ in, const short* __restrict__ wt,
                               const float* __restrict__ bias, short* __restrict__ out) {
    __shared__ short ldsA[6 * 130 * 4 * 8];      // 49,920 B
    __shared__ short ldsW[9 * COUT * 32];        // COUT=128: 73,728 B
    const int WSLOTS = 9 * COUT * 4;             // 16B granules in the W slice
    const int WSTRIDE = 9 * COUT * 32;           // shorts per kc slice

    int t = threadIdx.x;
    int lane = t & 63, wid = t >> 6;
    int q = lane >> 4, col = lane & 15;
    int out_row = wid >> 1, col_off = (wid & 1) << 6;

    int wtile = blockIdx.x & 1;
    int rest = blockIdx.x >> 1;
    int htile = rest & 31, b = rest >> 5;
    int w0h = wtile << 7;                        // staged col range w0h .. w0h+129
    int row0 = htile << 2;                       // staged rows row0 .. row0+5

    const short* inbase = in + ((size_t)(b * 130 + row0) * 258 + w0h) * CIN_STR;

    f32x4 acc[4][NT] = {};

    for (int kc = 0; kc < KC; ++kc) {
        // ---- stage A: 3120 granules (r*520 + p*4 + s), chunk c=(s-p)&3 ----
        for (int i = t; i < 3120; i += 512) {
            int r = i / 520, rem = i % 520;
            int p = rem >> 2, s = rem & 3;
            int c = (s - p) & 3;
            if (LASTC == 4 || kc < KC - 1 || c < LASTC) {
                const short* g = inbase + ((size_t)r * 258 + p) * CIN_STR + kc * 32 + c * 8;
                async16(g, ldsA + (size_t)(i & ~63) * 8);
            }
        }
        // ---- stage W: identity copy of the kc slice ----
        {
            const short* wsrc = wt + (size_t)kc * WSTRIDE;
            for (int i = t; i < WSLOTS; i += 512)
                async16(wsrc + (size_t)i * 8, ldsW + (size_t)(i & ~63) * 8);
        }
        __syncthreads();

#pragma unroll
        for (int dy = 0; dy < 3; ++dy) {
#pragma unroll
            for (int dx = 0; dx < 3; ++dx) {
                int ldsrow = out_row + dy;
                short8 a[4], bfr[NT];
#pragma unroll
                for (int mt = 0; mt < 4; ++mt) {
                    int p = col_off + mt * 16 + col + dx;
                    a[mt] = *(const short8*)(ldsA +
                        (size_t)(((ldsrow * 130 + p) << 2) + ((q + p) & 3)) * 8);
                }
                const short* wp = ldsW + (size_t)(dy * 3 + dx) * COUT * 32;
#pragma unroll
                for (int nt = 0; nt < NT; ++nt)
                    bfr[nt] = *(const short8*)(wp + (nt * 16 + col) * 32 + q * 8);
#pragma unroll
                for (int mt = 0; mt < 4; ++mt)
#pragma unroll
                    for (int nt = 0; nt < NT; ++nt)
                        acc[mt][nt] = __builtin_amdgcn_mfma_f32_16x16x32_bf16(
                            a[mt], bfr[nt], acc[mt][nt], 0, 0, 0);
            }
        }
        __syncthreads();
    }

    // ---- epilogue: D[m = mt*16 + q*4 + rr][n = nt*16 + col], leaky-relu, bf16 ----
    size_t obase = ((size_t)(b * 130 + row0 + 1 + out_row) * 258 + (w0h + 1 + col_off)) * COUT;
#pragma unroll
    for (int nt = 0; nt < NT; ++nt) {
        int n = nt * 16 + col;
        float bv = bias[n];
#pragma unroll
        for (int mt = 0; mt < 4; ++mt) {
#pragma unroll
            for (int rr = 0; rr < 4; ++rr) {
                int m = mt * 16 + q * 4 + rr;
                float v = acc[mt][nt][rr] + bv;
                v = (v >= 0.f) ? v : LEAK * v;
                out[obase + (size_t)m * COUT + n] = (short)f2b(v);
            }
        }
    }
}

// conv6: 3x3, Cin=32 (halo layout), Cout=1, linear, fp32 out (flat [B,H,W])
__global__ void conv6_kernel(const short* __restrict__ x, const float* __restrict__ k,
                             const float* __restrict__ bias, float* __restrict__ out) {
    __shared__ float wk[288];
    int t = threadIdx.x;
    for (int i = t; i < 288; i += 256) wk[i] = k[i];
    __syncthreads();
    int idx = blockIdx.x * 256 + t;
    int w = idx & 255, h = (idx >> 8) & 127, b = idx >> 15;
    float acc = bias[0];
#pragma unroll
    for (int dy = 0; dy < 3; ++dy) {
#pragma unroll
        for (int dx = 0; dx < 3; ++dx) {
            const short* xp = x + ((size_t)(b * 130 + h + dy) * 258 + (w + dx)) * 32;
            const float* wp = wk + (dy * 3 + dx) * 32;
#pragma unroll
            for (int c8 = 0; c8 < 4; ++c8) {
                short8 v = *(const short8*)(xp + c8 * 8);
#pragma unroll
                for (int j = 0; j < 8; ++j)
                    acc += b2f((unsigned short)v[j]) * wp[c8 * 8 + j];
            }
        }
    }
    out[idx] = acc;
}

extern "C" void kernel_launch(void* const* d_in, const int* in_sizes, int n_in,
                              void* d_out, int out_size, void* d_ws, size_t ws_size,
                              hipStream_t stream) {
    const float* left  = (const float*)d_in[0];
    const float* right = (const float*)d_in[1];
    const float* pd    = (const float*)d_in[2];
    const float* k[6];
    const float* bb[6];
    for (int i = 0; i < 6; ++i) { k[i] = (const float*)d_in[3 + 2 * i]; bb[i] = (const float*)d_in[4 + 2 * i]; }

    char* ws = (char*)d_ws;
    // weights: [0, 1 MiB)
    short* wt1 = (short*)ws;
    short* wt2 = (short*)(ws + 368640);
    short* wt3 = (short*)(ws + 663552);
    short* wt4 = (short*)(ws + 884736);
    short* wt5 = (short*)(ws + 995328);
    // region A @1 MiB: vol(C=144) -> X2(128) -> X4(64); region B: X1(128) -> X3(96) -> X5(32)
    short* vol = (short*)(ws + 1048576);
    short* X1  = (short*)(ws + 1048576 + 77276160);
    short* X2  = vol;
    short* X3  = X1;
    short* X4  = vol;
    short* X5  = X1;

    auto hz = [&](short* buf, int C) {
        int blocks = (8 * 772 * (C >> 3) + 255) / 256;
        halo_zero_one<<<blocks, 256, 0, stream>>>(buf, C);
    };

    prep_kernel<<<4096, 256, 0, stream>>>(left, right, pd, vol);
    wconv_all<<<dim3(720, 5), 256, 0, stream>>>(k[0], k[1], k[2], k[3], k[4],
                                                wt1, wt2, wt3, wt4, wt5);
    hz(vol, 144);
    hz(X1, 128);

    conv3x3_kernel<5, 144, 128, 8, 2><<<512, 512, 0, stream>>>(vol, wt1, bb[0], X1);
    hz(X2, 128);   // region A: only after conv1 finished reading vol
    conv3x3_kernel<4, 128, 128, 8, 4><<<512, 512, 0, stream>>>(X1, wt2, bb[1], X2);
    hz(X3, 96);    // region B: only after conv2 finished reading X1
    conv3x3_kernel<4, 128,  96, 6, 4><<<512, 512, 0, stream>>>(X2, wt3, bb[2], X3);
    hz(X4, 64);    // region A: only after conv3 finished reading X2
    conv3x3_kernel<3,  96,  64, 4, 4><<<512, 512, 0, stream>>>(X3, wt4, bb[3], X4);
    hz(X5, 32);    // region B: only after conv4 finished reading X3
    conv3x3_kernel<2,  64,  32, 2, 4><<<512, 512, 0, stream>>>(X4, wt5, bb[4], X5);
    conv6_kernel<<<1024, 256, 0, stream>>>(X5, k[5], bb[5], (float*)d_out);
}